// Round 1
// baseline (1036.294 us; speedup 1.0000x reference)
//
#include <hip/hip_runtime.h>
#include <cstdint>
#include <type_traits>

typedef unsigned short u16;
typedef __attribute__((ext_vector_type(8))) short bf16x8;
typedef __attribute__((ext_vector_type(4))) float f32x4;

__device__ __forceinline__ u16 f2bf(float f) {
  unsigned u = __float_as_uint(f);
  u += 0x7fffu + ((u >> 16) & 1u);
  return (u16)(u >> 16);
}
__device__ __forceinline__ float bf2f(u16 h) {
  return __uint_as_float(((unsigned)h) << 16);
}

// ---------------- elementwise f32 -> bf16 ----------------
__global__ __launch_bounds__(256) void k_f32_to_bf16(const float* __restrict__ in,
                                                     u16* __restrict__ out, int n4) {
  int i = blockIdx.x * 256 + threadIdx.x;
  if (i < n4) {
    float4 v = ((const float4*)in)[i];
    ushort4 o;
    o.x = f2bf(v.x); o.y = f2bf(v.y); o.z = f2bf(v.z); o.w = f2bf(v.w);
    ((ushort4*)out)[i] = o;
  }
}

// ---------------- transpose f32[R][C] -> bf16[C][R] ----------------
__global__ __launch_bounds__(256) void k_transpose_f32_bf16(const float* __restrict__ in,
                                                            u16* __restrict__ out,
                                                            int R, int C) {
  __shared__ float t[32][33];
  int tx = threadIdx.x & 31, ty = threadIdx.x >> 5;
  int c0 = blockIdx.x * 32, r0 = blockIdx.y * 32;
#pragma unroll
  for (int i = 0; i < 4; ++i)
    t[ty + 8 * i][tx] = in[(size_t)(r0 + ty + 8 * i) * C + c0 + tx];
  __syncthreads();
#pragma unroll
  for (int i = 0; i < 4; ++i)
    out[(size_t)(c0 + ty + 8 * i) * R + r0 + tx] = f2bf(t[tx][ty + 8 * i]);
}

// ---------------- GEMM: C[M][N] = A[M][K] * Bt[N][K]^T  (bf16 in, OutT out) ----------------
template <typename OutT>
__global__ __launch_bounds__(256) void k_gemm_bt(const u16* __restrict__ A,
                                                 const u16* __restrict__ B,
                                                 OutT* __restrict__ C,
                                                 int M, int N, int K) {
  __shared__ __align__(16) u16 As[128][40];
  __shared__ __align__(16) u16 Bs[128][40];
  int tid = threadIdx.x;
  int wave = tid >> 6, lane = tid & 63, quad = lane >> 4, l15 = lane & 15;
  int m0 = blockIdx.y * 128, n0 = blockIdx.x * 128;
  int wm = (wave >> 1) * 64, wn = (wave & 1) * 64;
  f32x4 acc[4][4] = {};
  for (int k0 = 0; k0 < K; k0 += 32) {
    __syncthreads();
#pragma unroll
    for (int c = 0; c < 2; ++c) {
      int chunk = tid + 256 * c;
      int row = chunk >> 2, col = (chunk & 3) * 8;
      *(uint4*)&As[row][col] = *(const uint4*)(A + (size_t)(m0 + row) * K + k0 + col);
      *(uint4*)&Bs[row][col] = *(const uint4*)(B + (size_t)(n0 + row) * K + k0 + col);
    }
    __syncthreads();
    bf16x8 af[4], bfr[4];
#pragma unroll
    for (int i = 0; i < 4; ++i) {
      af[i]  = *(const bf16x8*)&As[wm + i * 16 + l15][quad * 8];
      bfr[i] = *(const bf16x8*)&Bs[wn + i * 16 + l15][quad * 8];
    }
#pragma unroll
    for (int mt = 0; mt < 4; ++mt)
#pragma unroll
      for (int nt = 0; nt < 4; ++nt)
        acc[mt][nt] = __builtin_amdgcn_mfma_f32_16x16x32_bf16(af[mt], bfr[nt], acc[mt][nt], 0, 0, 0);
  }
#pragma unroll
  for (int mt = 0; mt < 4; ++mt)
#pragma unroll
    for (int nt = 0; nt < 4; ++nt) {
      int row = m0 + wm + mt * 16 + quad * 4;
      int col = n0 + wn + nt * 16 + l15;
#pragma unroll
      for (int r = 0; r < 4; ++r) {
        float v = acc[mt][nt][r];
        if constexpr (std::is_same<OutT, u16>::value)
          C[(size_t)(row + r) * N + col] = f2bf(v);
        else
          C[(size_t)(row + r) * N + col] = v;
      }
    }
}

// ---------------- RoPE in place on Q and K parts of QKV [4096][6144] ----------------
__global__ __launch_bounds__(256) void k_rope(u16* __restrict__ qkv) {
  int row = blockIdx.x;       // b*2048 + s
  int s = row & 2047;
  u16* base = qkv + (size_t)row * 6144;
  for (int p = threadIdx.x; p < 2560; p += 256) {
    int d, col;
    if (p < 2048) { d = p & 63; col = (p >> 6) * 128 + d; }
    else { int pk = p - 2048; d = pk & 63; col = 4096 + (pk >> 6) * 128 + d; }
    float f = exp2f((float)d * (-13.287712379549449f / 64.0f)); // 10000^(-d/64)
    float th = (float)s * f;
    float c = cosf(th), sn = sinf(th);
    float x1 = bf2f(base[col]), x2 = bf2f(base[col + 64]);
    base[col]      = f2bf(x1 * c - x2 * sn);
    base[col + 64] = f2bf(x2 * c + x1 * sn);
  }
}

// ---------------- V part of QKV -> Vt[b][kvh][d][s] ----------------
__global__ __launch_bounds__(256) void k_vt(const u16* __restrict__ qkv, u16* __restrict__ vt) {
  __shared__ u16 t[32][33];
  int tx = threadIdx.x & 31, ty = threadIdx.x >> 5;
  int s0 = blockIdx.x * 32, d0 = blockIdx.y * 32, g = blockIdx.z; // g = b*8+kvh
  int b = g >> 3, kvh = g & 7;
  const u16* in = qkv + (size_t)(b * 2048) * 6144 + 5120 + kvh * 128;
  u16* out = vt + (size_t)g * 128 * 2048;
#pragma unroll
  for (int i = 0; i < 4; ++i)
    t[ty + 8 * i][tx] = in[(size_t)(s0 + ty + 8 * i) * 6144 + d0 + tx];
  __syncthreads();
#pragma unroll
  for (int i = 0; i < 4; ++i)
    out[(size_t)(d0 + ty + 8 * i) * 2048 + s0 + tx] = t[tx][ty + 8 * i];
}

// ---------------- flash attention: 64 q-rows/block, 4 waves x 16 rows ----------------
__global__ __launch_bounds__(256) void k_flash(const u16* __restrict__ qkv,
                                               const u16* __restrict__ vt,
                                               u16* __restrict__ ao) {
  __shared__ __align__(16) u16 Ks[32][136];
  __shared__ __align__(16) u16 Vs[128][40];
  __shared__ __align__(16) u16 Ps[4][16][40];
  int tid = threadIdx.x, wave = tid >> 6, lane = tid & 63, quad = lane >> 4, l15 = lane & 15;
  int bh = blockIdx.x, b = bh >> 5, h = bh & 31, kvh = h >> 2;
  int q0 = blockIdx.y * 64;

  bf16x8 aq[4];
  {
    const u16* qp = qkv + (size_t)(b * 2048 + q0 + wave * 16 + l15) * 6144 + h * 128 + quad * 8;
#pragma unroll
    for (int c = 0; c < 4; ++c) aq[c] = *(const bf16x8*)(qp + c * 32);
  }
  f32x4 oacc[8] = {};
  float m_i[4], l_i[4];
#pragma unroll
  for (int r = 0; r < 4; ++r) { m_i[r] = -1e30f; l_i[r] = 0.f; }

  const u16* kbase = qkv + (size_t)(b * 2048) * 6144 + 4096 + kvh * 128;
  const u16* vbase = vt + (size_t)(b * 8 + kvh) * 128 * 2048;
  const float scale = 0.08838834764831845f; // 1/sqrt(128)
  int ktiles = (q0 + 64) / 32;
  int qg = q0 + wave * 16 + quad * 4;

  for (int kt = 0; kt < ktiles; ++kt) {
    int k0 = kt * 32;
    __syncthreads();
#pragma unroll
    for (int c = 0; c < 2; ++c) {
      int chunk = tid + 256 * c;
      { int r = chunk >> 4, col = (chunk & 15) * 8;
        *(uint4*)&Ks[r][col] = *(const uint4*)(kbase + (size_t)(k0 + r) * 6144 + col); }
      { int r = chunk >> 2, col = (chunk & 3) * 8;
        *(uint4*)&Vs[r][col] = *(const uint4*)(vbase + (size_t)r * 2048 + k0 + col); }
    }
    __syncthreads();
    f32x4 sacc[2] = {};
#pragma unroll
    for (int nt = 0; nt < 2; ++nt)
#pragma unroll
      for (int c = 0; c < 4; ++c) {
        bf16x8 bk = *(const bf16x8*)&Ks[nt * 16 + l15][c * 32 + quad * 8];
        sacc[nt] = __builtin_amdgcn_mfma_f32_16x16x32_bf16(aq[c], bk, sacc[nt], 0, 0, 0);
      }
    float p0[4], p1[4], rm[4];
#pragma unroll
    for (int r = 0; r < 4; ++r) {
      float s0v = sacc[0][r] * scale;
      float s1v = sacc[1][r] * scale;
      if (k0 + l15 > qg + r) s0v = -1e30f;
      if (k0 + 16 + l15 > qg + r) s1v = -1e30f;
      p0[r] = s0v; p1[r] = s1v;
      rm[r] = fmaxf(s0v, s1v);
    }
#pragma unroll
    for (int off = 8; off >= 1; off >>= 1)
#pragma unroll
      for (int r = 0; r < 4; ++r) rm[r] = fmaxf(rm[r], __shfl_xor(rm[r], off, 64));
    float alpha[4], rs[4];
#pragma unroll
    for (int r = 0; r < 4; ++r) {
      float mn = fmaxf(m_i[r], rm[r]);
      alpha[r] = exp2f((m_i[r] - mn) * 1.44269504f);
      m_i[r] = mn;
      p0[r] = exp2f((p0[r] - mn) * 1.44269504f);
      p1[r] = exp2f((p1[r] - mn) * 1.44269504f);
      rs[r] = p0[r] + p1[r];
    }
#pragma unroll
    for (int off = 8; off >= 1; off >>= 1)
#pragma unroll
      for (int r = 0; r < 4; ++r) rs[r] += __shfl_xor(rs[r], off, 64);
#pragma unroll
    for (int r = 0; r < 4; ++r) l_i[r] = l_i[r] * alpha[r] + rs[r];
#pragma unroll
    for (int o = 0; o < 8; ++o)
#pragma unroll
      for (int r = 0; r < 4; ++r) oacc[o][r] *= alpha[r];
#pragma unroll
    for (int r = 0; r < 4; ++r) {
      Ps[wave][quad * 4 + r][l15] = f2bf(p0[r]);
      Ps[wave][quad * 4 + r][16 + l15] = f2bf(p1[r]);
    }
    __syncthreads();
    bf16x8 ap = *(const bf16x8*)&Ps[wave][l15][quad * 8];
#pragma unroll
    for (int o = 0; o < 8; ++o) {
      bf16x8 bv = *(const bf16x8*)&Vs[o * 16 + l15][quad * 8];
      oacc[o] = __builtin_amdgcn_mfma_f32_16x16x32_bf16(ap, bv, oacc[o], 0, 0, 0);
    }
  }
  u16* op = ao + (size_t)(b * 2048 + q0 + wave * 16 + quad * 4) * 4096 + h * 128 + l15;
#pragma unroll
  for (int r = 0; r < 4; ++r) {
    float inv = 1.0f / l_i[r];
#pragma unroll
    for (int o = 0; o < 8; ++o)
      op[(size_t)r * 4096 + o * 16] = f2bf(oacc[o][r] * inv);
  }
}

// ---------------- launch ----------------
extern "C" void kernel_launch(void* const* d_in, const int* in_sizes, int n_in,
                              void* d_out, int out_size, void* d_ws, size_t ws_size,
                              hipStream_t stream) {
  const float* X  = (const float*)d_in[0];
  // d_in[1] = attention_mask (causal, hardcoded), d_in[2] = position_ids (arange, hardcoded)
  const float* Wq = (const float*)d_in[3];
  const float* Wk = (const float*)d_in[4];
  const float* Wv = (const float*)d_in[5];
  const float* Wo = (const float*)d_in[6];
  float* out = (float*)d_out;

  char* ws = (char*)d_ws;
  u16* Xb     = (u16*)(ws);                         // [4096][4096]      32 MB
  u16* WqkvT  = (u16*)(ws + 33554432ull);           // [6144][4096]      48 MB
  u16* WoT    = (u16*)(ws + 83886080ull);           // [4096][4096]      32 MB
  u16* QKV    = (u16*)(ws + 117440512ull);          // [4096][6144]      48 MB
  u16* Vt     = (u16*)(ws + 167772160ull);          // [16][128][2048]    8 MB
  u16* AO     = (u16*)(ws + 176160768ull);          // [4096][4096]      32 MB

  k_f32_to_bf16<<<16384, 256, 0, stream>>>(X, Xb, 4194304);
  k_transpose_f32_bf16<<<dim3(128, 128), 256, 0, stream>>>(Wq, WqkvT, 4096, 4096);
  k_transpose_f32_bf16<<<dim3(32, 128), 256, 0, stream>>>(Wk, WqkvT + (size_t)4096 * 4096, 4096, 1024);
  k_transpose_f32_bf16<<<dim3(32, 128), 256, 0, stream>>>(Wv, WqkvT + (size_t)5120 * 4096, 4096, 1024);
  k_transpose_f32_bf16<<<dim3(128, 128), 256, 0, stream>>>(Wo, WoT, 4096, 4096);
  k_gemm_bt<u16><<<dim3(48, 32), 256, 0, stream>>>(Xb, WqkvT, QKV, 4096, 6144, 4096);
  k_rope<<<4096, 256, 0, stream>>>(QKV);
  k_vt<<<dim3(64, 4, 16), 256, 0, stream>>>(QKV, Vt);
  k_flash<<<dim3(64, 32), 256, 0, stream>>>(QKV, Vt, AO);
  k_gemm_bt<float><<<dim3(32, 32), 256, 0, stream>>>(AO, WoT, out, 4096, 4096, 4096);
}

// Round 2
// 1019.128 us; speedup vs baseline: 1.0168x; 1.0168x over previous
//
#include <hip/hip_runtime.h>
#include <cstdint>
#include <type_traits>

typedef unsigned short u16;
typedef __attribute__((ext_vector_type(8))) short bf16x8;
typedef __attribute__((ext_vector_type(4))) float f32x4;

__device__ __forceinline__ u16 f2bf(float f) {
  unsigned u = __float_as_uint(f);
  u += 0x7fffu + ((u >> 16) & 1u);
  return (u16)(u >> 16);
}
__device__ __forceinline__ float bf2f(u16 h) {
  return __uint_as_float(((unsigned)h) << 16);
}

// async global->LDS, 16B per lane; LDS dest = wave-uniform base + lane*16
__device__ __forceinline__ void glds16(const u16* g, u16* l) {
  __builtin_amdgcn_global_load_lds((const __attribute__((address_space(1))) void*)g,
                                   (__attribute__((address_space(3))) void*)l,
                                   16, 0, 0);
}

// ---------------- elementwise f32 -> bf16 ----------------
__global__ __launch_bounds__(256) void k_f32_to_bf16(const float* __restrict__ in,
                                                     u16* __restrict__ out, int n4) {
  int i = blockIdx.x * 256 + threadIdx.x;
  if (i < n4) {
    float4 v = ((const float4*)in)[i];
    ushort4 o;
    o.x = f2bf(v.x); o.y = f2bf(v.y); o.z = f2bf(v.z); o.w = f2bf(v.w);
    ((ushort4*)out)[i] = o;
  }
}

// ---------------- transpose f32[R][C] -> bf16[C][R] ----------------
__global__ __launch_bounds__(256) void k_transpose_f32_bf16(const float* __restrict__ in,
                                                            u16* __restrict__ out,
                                                            int R, int C) {
  __shared__ float t[32][33];
  int tx = threadIdx.x & 31, ty = threadIdx.x >> 5;
  int c0 = blockIdx.x * 32, r0 = blockIdx.y * 32;
#pragma unroll
  for (int i = 0; i < 4; ++i)
    t[ty + 8 * i][tx] = in[(size_t)(r0 + ty + 8 * i) * C + c0 + tx];
  __syncthreads();
#pragma unroll
  for (int i = 0; i < 4; ++i)
    out[(size_t)(c0 + ty + 8 * i) * R + r0 + tx] = f2bf(t[tx][ty + 8 * i]);
}

// ---------------- GEMM: C[M][N] = A[M][K] * Bt[N][K]^T  (bf16 in, OutT out) ----------------
// m97-style: global_load_lds width=16 staging into unpadded [128][32] tiles,
// XOR-swizzled chunk placement (source-side) so fragment ds_read_b128 is
// uniform 2-way (free) instead of 8-way conflicted.
template <typename OutT>
__global__ __launch_bounds__(256) void k_gemm_bt(const u16* __restrict__ A,
                                                 const u16* __restrict__ B,
                                                 OutT* __restrict__ C,
                                                 int M, int N, int K) {
  __shared__ __align__(16) u16 As[128][32];
  __shared__ __align__(16) u16 Bs[128][32];
  int tid = threadIdx.x;
  int wave = tid >> 6, lane = tid & 63, quad = lane >> 4, l15 = lane & 15;
  int m0 = blockIdx.y * 128, n0 = blockIdx.x * 128;
  int wm = (wave >> 1) * 64, wn = (wave & 1) * 64;

  // staging: wave w covers rows w*32..w*32+31 (two 16-row calls per matrix).
  // lane -> row = base + lane/4, fetches global chunk (lane&3)^((lane>>3)&3)
  // so LDS slot (r, c) holds global chunk c ^ ((r>>1)&3).
  int rowoff = lane >> 2;
  int gcol = (((lane & 3) ^ ((lane >> 3) & 3)) * 8);
  const u16* Ag = A + (size_t)(m0 + wave * 32 + rowoff) * K + gcol;
  const u16* Bg = B + (size_t)(n0 + wave * 32 + rowoff) * K + gcol;
  u16* AsBase = &As[wave * 32][0];
  u16* BsBase = &Bs[wave * 32][0];
  const size_t rstride = (size_t)16 * K;

  // fragment read chunk: global chunk `quad` at row r lives in slot quad^((r>>1)&3);
  // for our rows (r>>1)&3 == (l15>>1)&3.
  int rchunk = (quad ^ ((l15 >> 1) & 3)) * 8;

  f32x4 acc[4][4] = {};
  for (int k0 = 0; k0 < K; k0 += 32) {
    __syncthreads();
    glds16(Ag + k0, AsBase);
    glds16(Ag + k0 + rstride, AsBase + 16 * 32);
    glds16(Bg + k0, BsBase);
    glds16(Bg + k0 + rstride, BsBase + 16 * 32);
    __syncthreads();
    bf16x8 af[4], bfr[4];
#pragma unroll
    for (int i = 0; i < 4; ++i) {
      af[i]  = *(const bf16x8*)&As[wm + i * 16 + l15][rchunk];
      bfr[i] = *(const bf16x8*)&Bs[wn + i * 16 + l15][rchunk];
    }
#pragma unroll
    for (int mt = 0; mt < 4; ++mt)
#pragma unroll
      for (int nt = 0; nt < 4; ++nt)
        acc[mt][nt] = __builtin_amdgcn_mfma_f32_16x16x32_bf16(af[mt], bfr[nt], acc[mt][nt], 0, 0, 0);
  }
#pragma unroll
  for (int mt = 0; mt < 4; ++mt)
#pragma unroll
    for (int nt = 0; nt < 4; ++nt) {
      int row = m0 + wm + mt * 16 + quad * 4;
      int col = n0 + wn + nt * 16 + l15;
#pragma unroll
      for (int r = 0; r < 4; ++r) {
        float v = acc[mt][nt][r];
        if constexpr (std::is_same<OutT, u16>::value)
          C[(size_t)(row + r) * N + col] = f2bf(v);
        else
          C[(size_t)(row + r) * N + col] = v;
      }
    }
}

// ---------------- RoPE in place on Q and K parts of QKV [4096][6144] ----------------
__global__ __launch_bounds__(256) void k_rope(u16* __restrict__ qkv) {
  int row = blockIdx.x;       // b*2048 + s
  int s = row & 2047;
  u16* base = qkv + (size_t)row * 6144;
  for (int p = threadIdx.x; p < 2560; p += 256) {
    int d, col;
    if (p < 2048) { d = p & 63; col = (p >> 6) * 128 + d; }
    else { int pk = p - 2048; d = pk & 63; col = 4096 + (pk >> 6) * 128 + d; }
    float f = exp2f((float)d * (-13.287712379549449f / 64.0f)); // 10000^(-d/64)
    float th = (float)s * f;
    float c = cosf(th), sn = sinf(th);
    float x1 = bf2f(base[col]), x2 = bf2f(base[col + 64]);
    base[col]      = f2bf(x1 * c - x2 * sn);
    base[col + 64] = f2bf(x2 * c + x1 * sn);
  }
}

// ---------------- V part of QKV -> Vt[b][kvh][d][s] ----------------
__global__ __launch_bounds__(256) void k_vt(const u16* __restrict__ qkv, u16* __restrict__ vt) {
  __shared__ u16 t[32][33];
  int tx = threadIdx.x & 31, ty = threadIdx.x >> 5;
  int s0 = blockIdx.x * 32, d0 = blockIdx.y * 32, g = blockIdx.z; // g = b*8+kvh
  int b = g >> 3, kvh = g & 7;
  const u16* in = qkv + (size_t)(b * 2048) * 6144 + 5120 + kvh * 128;
  u16* out = vt + (size_t)g * 128 * 2048;
#pragma unroll
  for (int i = 0; i < 4; ++i)
    t[ty + 8 * i][tx] = in[(size_t)(s0 + ty + 8 * i) * 6144 + d0 + tx];
  __syncthreads();
#pragma unroll
  for (int i = 0; i < 4; ++i)
    out[(size_t)(d0 + ty + 8 * i) * 2048 + s0 + tx] = t[tx][ty + 8 * i];
}

// ---------------- flash attention: 64 q-rows/block, 4 waves x 16 rows ----------------
__global__ __launch_bounds__(256) void k_flash(const u16* __restrict__ qkv,
                                               const u16* __restrict__ vt,
                                               u16* __restrict__ ao) {
  __shared__ __align__(16) u16 Ks[32][136];
  __shared__ __align__(16) u16 Vs[128][40];
  __shared__ __align__(16) u16 Ps[4][16][40];
  int tid = threadIdx.x, wave = tid >> 6, lane = tid & 63, quad = lane >> 4, l15 = lane & 15;
  int bh = blockIdx.x, b = bh >> 5, h = bh & 31, kvh = h >> 2;
  int q0 = blockIdx.y * 64;

  bf16x8 aq[4];
  {
    const u16* qp = qkv + (size_t)(b * 2048 + q0 + wave * 16 + l15) * 6144 + h * 128 + quad * 8;
#pragma unroll
    for (int c = 0; c < 4; ++c) aq[c] = *(const bf16x8*)(qp + c * 32);
  }
  f32x4 oacc[8] = {};
  float m_i[4], l_i[4];
#pragma unroll
  for (int r = 0; r < 4; ++r) { m_i[r] = -1e30f; l_i[r] = 0.f; }

  const u16* kbase = qkv + (size_t)(b * 2048) * 6144 + 4096 + kvh * 128;
  const u16* vbase = vt + (size_t)(b * 8 + kvh) * 128 * 2048;
  const float scale = 0.08838834764831845f; // 1/sqrt(128)
  int ktiles = (q0 + 64) / 32;
  int qg = q0 + wave * 16 + quad * 4;

  for (int kt = 0; kt < ktiles; ++kt) {
    int k0 = kt * 32;
    __syncthreads();
#pragma unroll
    for (int c = 0; c < 2; ++c) {
      int chunk = tid + 256 * c;
      { int r = chunk >> 4, col = (chunk & 15) * 8;
        *(uint4*)&Ks[r][col] = *(const uint4*)(kbase + (size_t)(k0 + r) * 6144 + col); }
      { int r = chunk >> 2, col = (chunk & 3) * 8;
        *(uint4*)&Vs[r][col] = *(const uint4*)(vbase + (size_t)r * 2048 + k0 + col); }
    }
    __syncthreads();
    f32x4 sacc[2] = {};
#pragma unroll
    for (int nt = 0; nt < 2; ++nt)
#pragma unroll
      for (int c = 0; c < 4; ++c) {
        bf16x8 bk = *(const bf16x8*)&Ks[nt * 16 + l15][c * 32 + quad * 8];
        sacc[nt] = __builtin_amdgcn_mfma_f32_16x16x32_bf16(aq[c], bk, sacc[nt], 0, 0, 0);
      }
    float p0[4], p1[4], rm[4];
#pragma unroll
    for (int r = 0; r < 4; ++r) {
      float s0v = sacc[0][r] * scale;
      float s1v = sacc[1][r] * scale;
      if (k0 + l15 > qg + r) s0v = -1e30f;
      if (k0 + 16 + l15 > qg + r) s1v = -1e30f;
      p0[r] = s0v; p1[r] = s1v;
      rm[r] = fmaxf(s0v, s1v);
    }
#pragma unroll
    for (int off = 8; off >= 1; off >>= 1)
#pragma unroll
      for (int r = 0; r < 4; ++r) rm[r] = fmaxf(rm[r], __shfl_xor(rm[r], off, 64));
    float alpha[4], rs[4];
#pragma unroll
    for (int r = 0; r < 4; ++r) {
      float mn = fmaxf(m_i[r], rm[r]);
      alpha[r] = exp2f((m_i[r] - mn) * 1.44269504f);
      m_i[r] = mn;
      p0[r] = exp2f((p0[r] - mn) * 1.44269504f);
      p1[r] = exp2f((p1[r] - mn) * 1.44269504f);
      rs[r] = p0[r] + p1[r];
    }
#pragma unroll
    for (int off = 8; off >= 1; off >>= 1)
#pragma unroll
      for (int r = 0; r < 4; ++r) rs[r] += __shfl_xor(rs[r], off, 64);
#pragma unroll
    for (int r = 0; r < 4; ++r) l_i[r] = l_i[r] * alpha[r] + rs[r];
#pragma unroll
    for (int o = 0; o < 8; ++o)
#pragma unroll
      for (int r = 0; r < 4; ++r) oacc[o][r] *= alpha[r];
#pragma unroll
    for (int r = 0; r < 4; ++r) {
      Ps[wave][quad * 4 + r][l15] = f2bf(p0[r]);
      Ps[wave][quad * 4 + r][16 + l15] = f2bf(p1[r]);
    }
    __syncthreads();
    bf16x8 ap = *(const bf16x8*)&Ps[wave][l15][quad * 8];
#pragma unroll
    for (int o = 0; o < 8; ++o) {
      bf16x8 bv = *(const bf16x8*)&Vs[o * 16 + l15][quad * 8];
      oacc[o] = __builtin_amdgcn_mfma_f32_16x16x32_bf16(ap, bv, oacc[o], 0, 0, 0);
    }
  }
  u16* op = ao + (size_t)(b * 2048 + q0 + wave * 16 + quad * 4) * 4096 + h * 128 + l15;
#pragma unroll
  for (int r = 0; r < 4; ++r) {
    float inv = 1.0f / l_i[r];
#pragma unroll
    for (int o = 0; o < 8; ++o)
      op[(size_t)r * 4096 + o * 16] = f2bf(oacc[o][r] * inv);
  }
}

// ---------------- launch ----------------
extern "C" void kernel_launch(void* const* d_in, const int* in_sizes, int n_in,
                              void* d_out, int out_size, void* d_ws, size_t ws_size,
                              hipStream_t stream) {
  const float* X  = (const float*)d_in[0];
  // d_in[1] = attention_mask (causal, hardcoded), d_in[2] = position_ids (arange, hardcoded)
  const float* Wq = (const float*)d_in[3];
  const float* Wk = (const float*)d_in[4];
  const float* Wv = (const float*)d_in[5];
  const float* Wo = (const float*)d_in[6];
  float* out = (float*)d_out;

  char* ws = (char*)d_ws;
  u16* Xb     = (u16*)(ws);                         // [4096][4096]      32 MB
  u16* WqkvT  = (u16*)(ws + 33554432ull);           // [6144][4096]      48 MB
  u16* WoT    = (u16*)(ws + 83886080ull);           // [4096][4096]      32 MB
  u16* QKV    = (u16*)(ws + 117440512ull);          // [4096][6144]      48 MB
  u16* Vt     = (u16*)(ws + 167772160ull);          // [16][128][2048]    8 MB
  u16* AO     = (u16*)(ws + 176160768ull);          // [4096][4096]      32 MB

  k_f32_to_bf16<<<16384, 256, 0, stream>>>(X, Xb, 4194304);
  k_transpose_f32_bf16<<<dim3(128, 128), 256, 0, stream>>>(Wq, WqkvT, 4096, 4096);
  k_transpose_f32_bf16<<<dim3(32, 128), 256, 0, stream>>>(Wk, WqkvT + (size_t)4096 * 4096, 4096, 1024);
  k_transpose_f32_bf16<<<dim3(32, 128), 256, 0, stream>>>(Wv, WqkvT + (size_t)5120 * 4096, 4096, 1024);
  k_transpose_f32_bf16<<<dim3(128, 128), 256, 0, stream>>>(Wo, WoT, 4096, 4096);
  k_gemm_bt<u16><<<dim3(48, 32), 256, 0, stream>>>(Xb, WqkvT, QKV, 4096, 6144, 4096);
  k_rope<<<4096, 256, 0, stream>>>(QKV);
  k_vt<<<dim3(64, 4, 16), 256, 0, stream>>>(QKV, Vt);
  k_flash<<<dim3(64, 32), 256, 0, stream>>>(QKV, Vt, AO);
  k_gemm_bt<float><<<dim3(32, 32), 256, 0, stream>>>(AO, WoT, out, 4096, 4096, 4096);
}